// Round 4
// baseline (252.861 us; speedup 1.0000x reference)
//
#include <hip/hip_runtime.h>

#define NCOLS 65536
#define NROWS 256
#define HID 64
#define THREADS 256            // 4 waves
#define NWAVES 4
#define COLS_PER_BLOCK 256     // 64 cols per wave
#define ROWS_PER_BLOCK 32
#define RCHUNK 4               // rows per register buffer
#define NCHUNKS (ROWS_PER_BLOCK / RCHUNK)   // 8, even
#define QCAP 192               // ring capacity: qlen<=127 before append, +<=64 per row

typedef float v2f __attribute__((ext_vector_type(2)));

__global__ __launch_bounds__(THREADS, 8) void soen_kernel(
    const float* __restrict__ phi, const float* __restrict__ s,
    const float* __restrict__ i_b, const float* __restrict__ w1,
    const float* __restrict__ b1, const float* __restrict__ w2,
    const float* __restrict__ b2, const int* __restrict__ func_idx,
    float* __restrict__ out)
{
    __shared__ float4 wpk[HID];            // {2*w1[0][j], 2*w1[1][j], 2*w1[2][j], 2*b1[j]}
    __shared__ float  w2m2[HID];           // -2*w2[j]
    __shared__ float  qp[NWAVES][QCAP];    // queued p
    __shared__ float  qs[NWAVES][QCAP];    // queued s
    __shared__ unsigned short qm[NWAVES][QCAP]; // (row<<6)|lane
    __shared__ float  ibc[NWAVES][64];     // i_b per lane-column

    const int t = threadIdx.x;
    const int w = t >> 6;
    const int lane = t & 63;
    const int colbase = blockIdx.x * COLS_PER_BLOCK;
    const int rowbase = blockIdx.y * ROWS_PER_BLOCK;
    const int wcolbase = colbase + w * 64;
    const int col = wcolbase + lane;

    if (t < HID) {
        wpk[t] = make_float4(2.f * w1[t], 2.f * w1[HID + t], 2.f * w1[2 * HID + t],
                             2.f * b1[t]);
        w2m2[t] = -2.f * w2[t];
    }
    __syncthreads();

    const int idx = func_idx[col];
    const float ib = i_b[col];
    ibc[w][lane] = ib;
    const bool is3 = (idx == 3);
    const unsigned long long m3 = __ballot(is3);
    const int n3 = __popcll(m3);
    const int myci = __popcll(m3 & ((1ULL << lane) - 1ULL));

    const float b2v = b2[0];
    float sumb = b2v;                       // b2 + sum_j w2[j]
    #pragma unroll
    for (int j = 0; j < HID; j++) sumb -= 0.5f * w2m2[j];

    const float* pp  = phi + (size_t)rowbase * NCOLS + col;
    const float* ssp = s   + (size_t)rowbase * NCOLS + col;
    float*       pob = out + (size_t)rowbase * NCOLS + col;

    int head = 0, tail = 0, qlen = 0;

    // drain 'cnt' (<=128) queued elements starting at ring position hd
    auto drain = [&](int hd, int cnt) {
        int i0 = hd + lane;        if (i0 >= QCAP) i0 -= QCAP;
        int i1 = hd + 64 + lane;   if (i1 >= QCAP) i1 -= QCAP;
        const bool v0 = lane < cnt;
        const bool v1 = (64 + lane) < cnt;
        const float p0 = qp[w][i0], s0 = qs[w][i0];
        const float p1 = qp[w][i1], s1 = qs[w][i1];
        const int m0 = qm[w][i0], m1 = qm[w][i1];
        v2f P2; P2.x = p0; P2.y = p1;
        v2f S2; S2.x = s0; S2.y = s1;
        v2f IB; IB.x = ibc[w][m0 & 63]; IB.y = ibc[w][m1 & 63];
        v2f acc0 = {0.f, 0.f};
        v2f acc1 = {0.f, 0.f};
        #pragma unroll 4
        for (int j = 0; j < HID; j += 2) {
            const float4 W0 = wpk[j];
            v2f A0 = P2 * W0.x + (S2 * W0.y + (IB * W0.z + W0.w));   // = 2*a
            v2f U0;
            U0.x = __builtin_amdgcn_rcpf(1.f + __expf(A0.x));
            U0.y = __builtin_amdgcn_rcpf(1.f + __expf(A0.y));
            acc0 += U0 * w2m2[j];
            const float4 W1 = wpk[j + 1];
            v2f A1 = P2 * W1.x + (S2 * W1.y + (IB * W1.z + W1.w));
            v2f U1;
            U1.x = __builtin_amdgcn_rcpf(1.f + __expf(A1.x));
            U1.y = __builtin_amdgcn_rcpf(1.f + __expf(A1.y));
            acc1 += U1 * w2m2[j + 1];
        }
        v2f acc = acc0 + acc1;
        if (v0) {
            const int row = rowbase + (m0 >> 6);
            out[(size_t)row * NCOLS + (wcolbase + (m0 & 63))] = sumb + acc.x;
        }
        if (v1) {
            const int row = rowbase + (m1 >> 6);
            out[(size_t)row * NCOLS + (wcolbase + (m1 & 63))] = sumb + acc.y;
        }
    };

    // process RCHUNK rows whose (phi,s) are already in registers
    auto process = [&](const float (&ph)[RCHUNK], const float (&sv)[RCHUNK], int rb) {
        #pragma unroll
        for (int rr = 0; rr < RCHUNK; rr++) {
            const int r = rb + rr;
            const float p = ph[rr] - rintf(ph[rr]);   // half-to-even
            const float p2 = p * p;
            const float g0 = fmaxf(fabsf(p) - sv[rr], 0.f);
            const float tp = p * fmaf(p2, fmaf(p2, 0.13333333f, -0.33333333f), 1.f);
            const float g1 = fmaf(-tp, sv[rr], tp);
            const float g2 = __expf(-10.f * p2) - sv[rr];
            const float res = (idx == 0) ? g0 : (idx == 1) ? g1 : g2;
            if (!is3) {
                pob[(size_t)r * NCOLS] = res;
            } else {
                int pos = tail + myci; if (pos >= QCAP) pos -= QCAP;
                qp[w][pos] = p;
                qs[w][pos] = sv[rr];
                qm[w][pos] = (unsigned short)((r << 6) | lane);
            }
            tail += n3; if (tail >= QCAP) tail -= QCAP;
            qlen += n3;
            if (qlen >= 128) {
                drain(head, 128);
                head += 128; if (head >= QCAP) head -= QCAP;
                qlen -= 128;
            }
        }
    };

    float phA[RCHUNK], svA[RCHUNK], phB[RCHUNK], svB[RCHUNK];

    #pragma unroll
    for (int i = 0; i < RCHUNK; i++) {
        phA[i] = pp[(size_t)i * NCOLS];
        svA[i] = ssp[(size_t)i * NCOLS];
    }

    #pragma unroll 1
    for (int c = 0; c < NCHUNKS; c += 2) {
        #pragma unroll
        for (int i = 0; i < RCHUNK; i++) {          // prefetch chunk c+1
            phB[i] = pp[(size_t)((c + 1) * RCHUNK + i) * NCOLS];
            svB[i] = ssp[(size_t)((c + 1) * RCHUNK + i) * NCOLS];
        }
        process(phA, svA, c * RCHUNK);
        if (c + 2 < NCHUNKS) {
            #pragma unroll
            for (int i = 0; i < RCHUNK; i++) {      // prefetch chunk c+2
                phA[i] = pp[(size_t)((c + 2) * RCHUNK + i) * NCOLS];
                svA[i] = ssp[(size_t)((c + 2) * RCHUNK + i) * NCOLS];
            }
        }
        process(phB, svB, (c + 1) * RCHUNK);
    }
    if (qlen > 0) drain(head, qlen);
}

extern "C" void kernel_launch(void* const* d_in, const int* in_sizes, int n_in,
                              void* d_out, int out_size, void* d_ws, size_t ws_size,
                              hipStream_t stream) {
    const float* phi      = (const float*)d_in[0];
    const float* s        = (const float*)d_in[1];
    const float* i_b      = (const float*)d_in[2];
    const float* w1       = (const float*)d_in[3];
    const float* b1       = (const float*)d_in[4];
    const float* w2       = (const float*)d_in[5];
    const float* b2       = (const float*)d_in[6];
    const int*   func_idx = (const int*)d_in[7];
    float* out = (float*)d_out;

    dim3 grid(NCOLS / COLS_PER_BLOCK, NROWS / ROWS_PER_BLOCK);
    soen_kernel<<<grid, dim3(THREADS), 0, stream>>>(phi, s, i_b, w1, b1, w2, b2,
                                                    func_idx, out);
}

// Round 5
// 243.860 us; speedup vs baseline: 1.0369x; 1.0369x over previous
//
#include <hip/hip_runtime.h>

#define NCOLS 65536
#define NROWS 256
#define HID 64
#define THREADS 256            // 4 waves
#define NWAVES 4
#define COLS_PER_BLOCK 256     // 64 cols per wave
#define ROWS_PER_BLOCK 16      // grid 4096 = 2x oversubscription
#define QCAP 192

typedef float v2f __attribute__((ext_vector_type(2)));

__global__ __launch_bounds__(THREADS, 4) void soen_kernel(
    const float* __restrict__ phi, const float* __restrict__ s,
    const float* __restrict__ i_b, const float* __restrict__ w1,
    const float* __restrict__ b1, const float* __restrict__ w2,
    const float* __restrict__ b2, const int* __restrict__ func_idx,
    float* __restrict__ out)
{
    __shared__ float4 wpk[HID];            // {c*w1[0][j], c*w1[1][j], c*w1[2][j], c*b1[j]}, c=2*log2e
    __shared__ float  w2m2[HID];           // -2*w2[j]
    __shared__ float  qp[NWAVES][QCAP];
    __shared__ float  qs[NWAVES][QCAP];
    __shared__ unsigned short qm[NWAVES][QCAP];   // (local_row<<6)|lane
    __shared__ float  ibc[NWAVES][64];
    __shared__ float  obuf[NWAVES][ROWS_PER_BLOCK][64];  // staged full rows

    const int t = threadIdx.x;
    const int w = t >> 6;
    const int lane = t & 63;
    const int colbase = blockIdx.x * COLS_PER_BLOCK;
    const int rowbase = blockIdx.y * ROWS_PER_BLOCK;
    const int col = colbase + w * 64 + lane;

    if (t < HID) {
        const float c = 2.8853900817779268f;   // 2*log2(e): tanh(a)=1-2/(1+exp2(c*a))
        wpk[t] = make_float4(c * w1[t], c * w1[HID + t], c * w1[2 * HID + t],
                             c * b1[t]);
        w2m2[t] = -2.f * w2[t];
    }
    __syncthreads();

    const int idx = func_idx[col];
    ibc[w][lane] = i_b[col];
    const bool is3 = (idx == 3);
    const unsigned long long m3 = __ballot(is3);
    const int n3 = __popcll(m3);
    const int myci = __popcll(m3 & ((1ULL << lane) - 1ULL));

    float sumb = b2[0];                    // b2 + sum_j w2[j]
    #pragma unroll
    for (int j = 0; j < HID; j++) sumb -= 0.5f * w2m2[j];

    const float* pp  = phi + (size_t)rowbase * NCOLS + col;
    const float* ssp = s   + (size_t)rowbase * NCOLS + col;
    float*       pob = out + (size_t)rowbase * NCOLS + col;

    int head = 0, tail = 0, qlen = 0, D = 0, srow = 0;

    // drain 'cnt' (<=128) queued elements starting at ring position hd -> obuf
    auto drain = [&](int hd, int cnt) {
        int i0 = hd + lane;        if (i0 >= QCAP) i0 -= QCAP;
        int i1 = hd + 64 + lane;   if (i1 >= QCAP) i1 -= QCAP;
        const bool v0 = lane < cnt;
        const bool v1 = (64 + lane) < cnt;
        const float p0 = qp[w][i0], s0 = qs[w][i0];
        const float p1 = qp[w][i1], s1 = qs[w][i1];
        const int m0 = qm[w][i0], m1 = qm[w][i1];
        v2f P2; P2.x = p0; P2.y = p1;
        v2f S2; S2.x = s0; S2.y = s1;
        v2f IB; IB.x = ibc[w][m0 & 63]; IB.y = ibc[w][m1 & 63];
        v2f acc0 = {0.f, 0.f};
        v2f acc1 = {0.f, 0.f};
        #pragma unroll 4
        for (int j = 0; j < HID; j += 2) {
            const float4 W0 = wpk[j];
            v2f A0 = P2 * W0.x + (S2 * W0.y + (IB * W0.z + W0.w));
            v2f U0;
            U0.x = __builtin_amdgcn_rcpf(1.f + __builtin_amdgcn_exp2f(A0.x));
            U0.y = __builtin_amdgcn_rcpf(1.f + __builtin_amdgcn_exp2f(A0.y));
            acc0 += U0 * w2m2[j];
            const float4 W1 = wpk[j + 1];
            v2f A1 = P2 * W1.x + (S2 * W1.y + (IB * W1.z + W1.w));
            v2f U1;
            U1.x = __builtin_amdgcn_rcpf(1.f + __builtin_amdgcn_exp2f(A1.x));
            U1.y = __builtin_amdgcn_rcpf(1.f + __builtin_amdgcn_exp2f(A1.y));
            acc1 += U1 * w2m2[j + 1];
        }
        v2f acc = acc0 + acc1;
        if (v0) obuf[w][m0 >> 6][m0 & 63] = sumb + acc.x;
        if (v1) obuf[w][m1 >> 6][m1 & 63] = sumb + acc.y;
    };

    #pragma unroll 2
    for (int r = 0; r < ROWS_PER_BLOCK; r++) {
        const float ph = pp[(size_t)r * NCOLS];
        const float sv = ssp[(size_t)r * NCOLS];
        const float p = ph - rintf(ph);          // half-to-even
        const float p2 = p * p;
        const float g0 = fmaxf(fabsf(p) - sv, 0.f);
        // tanh(p), |p|<=0.5, odd series err<5e-4
        const float tp = p * fmaf(p2, fmaf(p2, 0.13333333f, -0.33333333f), 1.f);
        const float g1 = fmaf(-tp, sv, tp);
        const float g2 = __builtin_amdgcn_exp2f(-14.426950408889634f * p2) - sv;
        const float res = (idx == 0) ? g0 : (idx == 1) ? g1 : g2;
        if (!is3) {
            obuf[w][r][lane] = res;
        } else {
            int pos = tail + myci; if (pos >= QCAP) pos -= QCAP;
            qp[w][pos] = p;
            qs[w][pos] = sv;
            qm[w][pos] = (unsigned short)((r << 6) | lane);
        }
        tail += n3; if (tail >= QCAP) tail -= QCAP;
        qlen += n3;
        if (qlen >= 128) {
            drain(head, 128);
            head += 128; if (head >= QCAP) head -= QCAP;
            qlen -= 128;
            D += 128;
        }
        // flush completed rows as full coalesced 256B wave-stores
        while (srow <= r && (srow + 1) * n3 <= D) {
            pob[(size_t)srow * NCOLS] = obuf[w][srow][lane];
            srow++;
        }
    }
    if (qlen > 0) { drain(head, qlen); D += qlen; }
    while (srow < ROWS_PER_BLOCK && (srow + 1) * n3 <= D) {
        pob[(size_t)srow * NCOLS] = obuf[w][srow][lane];
        srow++;
    }
}

extern "C" void kernel_launch(void* const* d_in, const int* in_sizes, int n_in,
                              void* d_out, int out_size, void* d_ws, size_t ws_size,
                              hipStream_t stream) {
    const float* phi      = (const float*)d_in[0];
    const float* s        = (const float*)d_in[1];
    const float* i_b      = (const float*)d_in[2];
    const float* w1       = (const float*)d_in[3];
    const float* b1       = (const float*)d_in[4];
    const float* w2       = (const float*)d_in[5];
    const float* b2       = (const float*)d_in[6];
    const int*   func_idx = (const int*)d_in[7];
    float* out = (float*)d_out;

    dim3 grid(NCOLS / COLS_PER_BLOCK, NROWS / ROWS_PER_BLOCK);
    soen_kernel<<<grid, dim3(THREADS), 0, stream>>>(phi, s, i_b, w1, b1, w2, b2,
                                                    func_idx, out);
}